// Round 1
// baseline (222.008 us; speedup 1.0000x reference)
//
#include <hip/hip_runtime.h>
#include <stdint.h>

typedef _Float16 f16;
typedef __attribute__((ext_vector_type(8))) _Float16 f16x8;
typedef __attribute__((ext_vector_type(4))) float f32x4;
typedef __attribute__((ext_vector_type(2))) unsigned int u32x2;
typedef __attribute__((ext_vector_type(4))) unsigned int u32x4;
typedef decltype(__builtin_amdgcn_cvt_pkrtz(0.f, 0.f)) h2_t;

#define S_LEN 2048
#define BATCH 8
#define D_IN  1024
#define DHALF 512

// low 32 bits of a generic pointer into LDS == LDS byte offset on gfx9xx
__device__ __forceinline__ unsigned lds_off(const void* p) {
  return (unsigned)(size_t)p;
}

// ---------------------------------------------------------------------------
// Projection: out[s,b,e] = sum_d X[s,b,d] * W[e,d] + bias[e], stored fp16.
// GEMM view: A (M=16384, K=1024) row-major; B = W (N=512, K=1024) row-major
// (both K-contiguous). Tile 128x128x32, 4 waves, 64x64 per wave.
// f32 global loads -> cvt_pkrtz -> fp16 LDS (stride 40 = 80B, 2-way banks).
// ---------------------------------------------------------------------------
__global__ __launch_bounds__(256) void proj_kernel(
    const float* __restrict__ Xq, const float* __restrict__ Xk, const float* __restrict__ Xv,
    const float* __restrict__ Wq, const float* __restrict__ Wk, const float* __restrict__ Wv,
    const float* __restrict__ bq, const float* __restrict__ bk, const float* __restrict__ bv,
    f16* __restrict__ oq, f16* __restrict__ ok, f16* __restrict__ ov)
{
  const int z = blockIdx.z;
  const float* X    = (z == 0) ? Xq : (z == 1) ? Xk : Xv;
  const float* W    = (z == 0) ? Wq : (z == 1) ? Wk : Wv;
  const float* bias = (z == 0) ? bq : (z == 1) ? bk : bv;
  f16* out          = (z == 0) ? oq : (z == 1) ? ok : ov;

  const int m0 = blockIdx.x * 128;
  const int n0 = blockIdx.y * 128;
  const int tid = threadIdx.x;
  const int lane = tid & 63;
  const int wave = tid >> 6;
  const int wr = wave >> 1, wc = wave & 1;
  const int g = lane >> 4, rl = lane & 15;

  __shared__ f16 As[128 * 40];
  __shared__ f16 Bs[128 * 40];

  f32x4 acc[4][4];
#pragma unroll
  for (int i = 0; i < 4; i++)
#pragma unroll
    for (int j = 0; j < 4; j++) acc[i][j] = (f32x4){0.f, 0.f, 0.f, 0.f};

  const int srow = tid >> 1;            // 0..127
  const int sh   = (tid & 1) * 16;      // 0 / 16

  const float* gA = X + (size_t)(m0 + srow) * D_IN + sh;
  const float* gB = W + (size_t)(n0 + srow) * D_IN + sh;
  f16* wA = &As[srow * 40 + sh];
  f16* wB = &Bs[srow * 40 + sh];

  for (int k0 = 0; k0 < D_IN; k0 += 32) {
    __syncthreads();
    {
      f32x4 a0 = *(const f32x4*)(gA + k0);
      f32x4 a1 = *(const f32x4*)(gA + k0 + 4);
      f32x4 a2 = *(const f32x4*)(gA + k0 + 8);
      f32x4 a3 = *(const f32x4*)(gA + k0 + 12);
      f32x4 b0 = *(const f32x4*)(gB + k0);
      f32x4 b1 = *(const f32x4*)(gB + k0 + 4);
      f32x4 b2 = *(const f32x4*)(gB + k0 + 8);
      f32x4 b3 = *(const f32x4*)(gB + k0 + 12);
      union H8 { h2_t h2[4]; f16x8 v; };
      H8 pa0, pa1, pb0, pb1;
      pa0.h2[0] = __builtin_amdgcn_cvt_pkrtz(a0.x, a0.y);
      pa0.h2[1] = __builtin_amdgcn_cvt_pkrtz(a0.z, a0.w);
      pa0.h2[2] = __builtin_amdgcn_cvt_pkrtz(a1.x, a1.y);
      pa0.h2[3] = __builtin_amdgcn_cvt_pkrtz(a1.z, a1.w);
      pa1.h2[0] = __builtin_amdgcn_cvt_pkrtz(a2.x, a2.y);
      pa1.h2[1] = __builtin_amdgcn_cvt_pkrtz(a2.z, a2.w);
      pa1.h2[2] = __builtin_amdgcn_cvt_pkrtz(a3.x, a3.y);
      pa1.h2[3] = __builtin_amdgcn_cvt_pkrtz(a3.z, a3.w);
      pb0.h2[0] = __builtin_amdgcn_cvt_pkrtz(b0.x, b0.y);
      pb0.h2[1] = __builtin_amdgcn_cvt_pkrtz(b0.z, b0.w);
      pb0.h2[2] = __builtin_amdgcn_cvt_pkrtz(b1.x, b1.y);
      pb0.h2[3] = __builtin_amdgcn_cvt_pkrtz(b1.z, b1.w);
      pb1.h2[0] = __builtin_amdgcn_cvt_pkrtz(b2.x, b2.y);
      pb1.h2[1] = __builtin_amdgcn_cvt_pkrtz(b2.z, b2.w);
      pb1.h2[2] = __builtin_amdgcn_cvt_pkrtz(b3.x, b3.y);
      pb1.h2[3] = __builtin_amdgcn_cvt_pkrtz(b3.z, b3.w);
      *(f16x8*)wA       = pa0.v;
      *(f16x8*)(wA + 8) = pa1.v;
      *(f16x8*)wB       = pb0.v;
      *(f16x8*)(wB + 8) = pb1.v;
    }
    __syncthreads();

    f16x8 af[4], bf[4];
#pragma unroll
    for (int i = 0; i < 4; i++)
      af[i] = *(const f16x8*)&As[(wr * 64 + i * 16 + rl) * 40 + g * 8];
#pragma unroll
    for (int j = 0; j < 4; j++)
      bf[j] = *(const f16x8*)&Bs[(wc * 64 + j * 16 + rl) * 40 + g * 8];
#pragma unroll
    for (int i = 0; i < 4; i++)
#pragma unroll
      for (int j = 0; j < 4; j++)
        acc[i][j] = __builtin_amdgcn_mfma_f32_16x16x32_f16(af[i], bf[j], acc[i][j], 0, 0, 0);
  }

  // epilogue: + bias, cast fp16 (RTN), C/D layout: col = lane&15, row = (lane>>4)*4 + r
#pragma unroll
  for (int i = 0; i < 4; i++) {
    const int row = m0 + wr * 64 + i * 16 + g * 4;
#pragma unroll
    for (int j = 0; j < 4; j++) {
      const int col = n0 + wc * 64 + j * 16 + rl;
      const float bb = bias[col];
#pragma unroll
      for (int r = 0; r < 4; r++)
        out[(size_t)(row + r) * DHALF + col] = (f16)(acc[i][j][r] + bb);
    }
  }
}

// ---------------------------------------------------------------------------
// Batched GEMM-TN: C[b] = A[b] (M x K, K-contig) * B[b] (K x N, N-contig).
// B is transpose-staged into [4k][16n] subtiles; phys block order
// {0,2,4,6,1,3,5,7} so ds_read_b64_tr_b16 (+offset:512) delivers the
// fp16 B-fragment (lane holds B[k=8g+j][n=l&15], j=0..7).
// EPI=0: apply attn mask, store f32 logits.  EPI=1: store f32 to out.
// ---------------------------------------------------------------------------
template <int EPI>
__global__ __launch_bounds__(256) void gemm_tn_kernel(
    const f16* __restrict__ A, long batchA, int lda,
    const f16* __restrict__ Bm, long batchB, int ldb,
    int Ksize,
    const int* __restrict__ mask,
    float* __restrict__ out, long batchOut, int ldo)
{
  const int bz = blockIdx.z;
  const int n0 = blockIdx.x * 128;
  const int m0 = blockIdx.y * 128;
  const f16* Ab = A + (size_t)bz * batchA;
  const f16* Bb = Bm + (size_t)bz * batchB;

  const int tid = threadIdx.x, lane = tid & 63, wave = tid >> 6;
  const int wr = wave >> 1, wc = wave & 1;
  const int g = lane >> 4, rl = lane & 15;

  __shared__ f16 As[128 * 40];   // padded stride 40
  __shared__ f16 Bs[32 * 128];   // [e_blk(8)][phys(8)] blocks of [4][16] fp16

  f32x4 acc[4][4];
#pragma unroll
  for (int i = 0; i < 4; i++)
#pragma unroll
    for (int j = 0; j < 4; j++) acc[i][j] = (f32x4){0.f, 0.f, 0.f, 0.f};

  const int arow = tid >> 1;
  const int ah   = (tid & 1) * 16;
  const int brow = tid >> 3;            // k-row 0..31
  const int bcol = (tid & 7) * 16;      // n offset 0..112
  const int sblk = brow >> 2;
  const int phys = ((sblk & 1) << 2) | (sblk >> 1);
  f16* wA = &As[arow * 40 + ah];
  f16* wB = (f16*)((char*)Bs + (size_t)(((tid & 7) * 8 + phys) * 128 + (brow & 3) * 32));
  const f16* gA = Ab + (size_t)(m0 + arow) * lda + ah;
  const f16* gB = Bb + (size_t)brow * ldb + n0 + bcol;

  const unsigned bs_base = lds_off(&Bs[0]);

  for (int k0 = 0; k0 < Ksize; k0 += 32) {
    __syncthreads();
    {
      f16x8 va0 = *(const f16x8*)(gA + k0);
      f16x8 va1 = *(const f16x8*)(gA + k0 + 8);
      const f16* gb = gB + (size_t)k0 * ldb;
      f16x8 vb0 = *(const f16x8*)(gb);
      f16x8 vb1 = *(const f16x8*)(gb + 8);
      *(f16x8*)wA       = va0;
      *(f16x8*)(wA + 8) = va1;
      *(f16x8*)wB       = vb0;
      *(f16x8*)(wB + 8) = vb1;
    }
    __syncthreads();

    f16x8 af[4];
#pragma unroll
    for (int i = 0; i < 4; i++)
      af[i] = *(const f16x8*)&As[(wr * 64 + i * 16 + rl) * 40 + g * 8];

    f16x8 bf[4];
#pragma unroll
    for (int j = 0; j < 4; j++) {
      unsigned addr = bs_base + (unsigned)((wc * 4 + j) * 1024) + (unsigned)lane * 8u;
      u32x2 lo, hi;
      asm volatile("ds_read_b64_tr_b16 %0, %1" : "=v"(lo) : "v"(addr));
      asm volatile("ds_read_b64_tr_b16 %0, %1 offset:512" : "=v"(hi) : "v"(addr));
      union { u32x4 u; f16x8 h; } cc;
      cc.u = (u32x4){lo.x, lo.y, hi.x, hi.y};
      bf[j] = cc.h;
    }
    // rule 18: fence tr-read results before register-only MFMA consumers
    asm volatile("s_waitcnt lgkmcnt(0)" ::: "memory");
    __builtin_amdgcn_sched_barrier(0);

#pragma unroll
    for (int i = 0; i < 4; i++)
#pragma unroll
      for (int j = 0; j < 4; j++)
        acc[i][j] = __builtin_amdgcn_mfma_f32_16x16x32_f16(af[i], bf[j], acc[i][j], 0, 0, 0);
  }

  float* ob = out + (size_t)bz * batchOut;
#pragma unroll
  for (int i = 0; i < 4; i++) {
    const int row = m0 + wr * 64 + i * 16 + g * 4;
#pragma unroll
    for (int j = 0; j < 4; j++) {
      const int col = n0 + wc * 64 + j * 16 + rl;
#pragma unroll
      for (int r = 0; r < 4; r++) {
        float val = acc[i][j][r];
        if (EPI == 0) {
          if (mask[(row + r) * DHALF + col] != 0) val = -1e30f;
        }
        ob[(size_t)(row + r) * ldo + col] = val;
      }
    }
  }
}

// ---------------------------------------------------------------------------
// Row softmax over e (512) for 4096 rows; one wave per row; fp16 output.
// ---------------------------------------------------------------------------
__global__ __launch_bounds__(256) void softmax_kernel(
    const float* __restrict__ logits, f16* __restrict__ P)
{
  const int row  = blockIdx.x * 4 + (threadIdx.x >> 6);
  const int lane = threadIdx.x & 63;
  const float* rp = logits + (size_t)row * DHALF + lane * 8;
  f32x4 x0 = *(const f32x4*)rp;
  f32x4 x1 = *(const f32x4*)(rp + 4);

  float m = fmaxf(fmaxf(fmaxf(x0.x, x0.y), fmaxf(x0.z, x0.w)),
                  fmaxf(fmaxf(x1.x, x1.y), fmaxf(x1.z, x1.w)));
#pragma unroll
  for (int off = 32; off > 0; off >>= 1) m = fmaxf(m, __shfl_xor(m, off, 64));

  float e0 = __expf(x0.x - m), e1 = __expf(x0.y - m);
  float e2 = __expf(x0.z - m), e3 = __expf(x0.w - m);
  float e4 = __expf(x1.x - m), e5 = __expf(x1.y - m);
  float e6 = __expf(x1.z - m), e7 = __expf(x1.w - m);
  float s = ((e0 + e1) + (e2 + e3)) + ((e4 + e5) + (e6 + e7));
#pragma unroll
  for (int off = 32; off > 0; off >>= 1) s += __shfl_xor(s, off, 64);
  const float inv = 1.0f / s;

  union { h2_t h2[4]; f16x8 v; } o;
  o.h2[0] = __builtin_amdgcn_cvt_pkrtz(e0 * inv, e1 * inv);
  o.h2[1] = __builtin_amdgcn_cvt_pkrtz(e2 * inv, e3 * inv);
  o.h2[2] = __builtin_amdgcn_cvt_pkrtz(e4 * inv, e5 * inv);
  o.h2[3] = __builtin_amdgcn_cvt_pkrtz(e6 * inv, e7 * inv);
  *(f16x8*)(P + (size_t)row * DHALF + lane * 8) = o.v;
}

// ---------------------------------------------------------------------------
extern "C" void kernel_launch(void* const* d_in, const int* in_sizes, int n_in,
                              void* d_out, int out_size, void* d_ws, size_t ws_size,
                              hipStream_t stream) {
  const float* q    = (const float*)d_in[0];
  const float* k    = (const float*)d_in[1];
  const float* v    = (const float*)d_in[2];
  const int*   mask = (const int*)d_in[3];
  const float* Wq   = (const float*)d_in[4];
  const float* bq   = (const float*)d_in[5];
  const float* Wk   = (const float*)d_in[6];
  const float* bk   = (const float*)d_in[7];
  const float* Wv   = (const float*)d_in[8];
  const float* bv   = (const float*)d_in[9];

  char* ws = (char*)d_ws;
  f16*   qt     = (f16*)(ws);                                  // 16 MB
  f16*   kt     = (f16*)(ws + 16777216);                       // 16 MB
  f16*   vt     = (f16*)(ws + 2 * 16777216);                   // 16 MB
  float* logits = (float*)(ws + 3 * 16777216);                 // 8 MB
  f16*   P      = (f16*)(ws + 3 * 16777216 + 8388608);         // 4 MB

  // 1) fused q/k/v projections -> fp16 (S,B,DH) flat
  proj_kernel<<<dim3(128, 4, 3), 256, 0, stream>>>(q, k, v, Wq, Wk, Wv, bq, bk, bv,
                                                   qt, kt, vt);
  // 2) logits[b,d,e] = sum_s q_[b,d,s] k_[b,s,e]  (+mask -> -1e30)
  gemm_tn_kernel<0><<<dim3(4, 4, 8), 256, 0, stream>>>(
      qt, 1048576L, 2048, kt, 1048576L, 512, 2048, mask, logits, 262144L, 512);
  // 3) P = softmax(logits) over e, fp16
  softmax_kernel<<<dim3(1024), 256, 0, stream>>>(logits, P);
  // 4) out[b,d,s] = sum_e P[b,d,e] v_[b,e,s]  -> f32 d_out
  gemm_tn_kernel<1><<<dim3(16, 4, 8), 256, 0, stream>>>(
      P, 262144L, 512, vt, 1048576L, 2048, 512, nullptr, (float*)d_out, 1048576L, 2048);
}